// Round 5
// baseline (95.420 us; speedup 1.0000x reference)
//
#include <hip/hip_runtime.h>
#include <hip/hip_bf16.h>

typedef unsigned short u16;
typedef __attribute__((ext_vector_type(8))) short bhalf8;
typedef __attribute__((ext_vector_type(4))) float fx4;

struct __align__(8) US4 { u16 v[4]; };

__device__ __forceinline__ u16 f2bf(float x) {
  union { float f; unsigned int u; } c; c.f = x;
  unsigned int r = c.u + 0x7FFFu + ((c.u >> 16) & 1u);
  return (u16)(r >> 16);
}

__device__ __forceinline__ void gload16(const void* g, void* l) {
  __builtin_amdgcn_global_load_lds((const __attribute__((address_space(1))) void*)g,
                                   (__attribute__((address_space(3))) void*)l,
                                   16, 0, 0);
}

#define MFMA16(a, b, c) __builtin_amdgcn_mfma_f32_16x16x32_bf16((a), (b), (c), 0, 0, 0)
#define FENCE() asm volatile("" ::: "memory")

// ---------------- input conversion ----------------
__global__ void k_conv(const float* __restrict__ in, u16* __restrict__ out, int n4) {
  int i = blockIdx.x * 256 + threadIdx.x;
  if (i < n4) {
    float4 v = ((const float4*)in)[i];
    US4 o;
    o.v[0] = f2bf(v.x); o.v[1] = f2bf(v.y); o.v[2] = f2bf(v.z); o.v[3] = f2bf(v.w);
    ((US4*)out)[i] = o;
  }
}

// transpose [R][C] f32 -> [C][R] bf16, 64x64 tiles.
// remap!=0: output rows >=512 get per-head K/V interleave:
//   K col c in [512,1024)  -> 512 + h*128 +      (c-512)%64
//   V col c in [1024,1536) -> 512 + h*128 + 64 + (c-1024)%64
__global__ void k_transpose(const float* __restrict__ in, u16* __restrict__ out,
                            int R, int C, int rtiles, int remap) {
  __shared__ float tile[64][65];
  const int bx = blockIdx.x;
  const int rt = bx % rtiles, ct = bx / rtiles;
  const int r0 = rt * 64, c0 = ct * 64;
  const int t = threadIdx.x;
  #pragma unroll
  for (int i = 0; i < 16; ++i) {
    int e = i * 256 + t;
    int rr = e >> 6, cc = e & 63;
    tile[rr][cc] = in[(r0 + rr) * C + c0 + cc];
  }
  __syncthreads();
  #pragma unroll
  for (int i = 0; i < 16; ++i) {
    int e = i * 256 + t;
    int rr = e >> 6, cc = e & 63;
    int orow = c0 + rr;
    if (remap && orow >= 512) {
      int region = (orow - 512) >> 9;       // 0=K, 1=V
      int within = (orow - 512) & 511;
      int h = within >> 6;
      orow = 512 + h * 128 + region * 64 + (within & 63);
    }
    out[orow * R + r0 + cc] = f2bf(tile[cc][rr]);
  }
}

// ---------------- 256x256 8-phase GEMM core (BK=64, 2 LDS dbuf, counted vmcnt) ----------------
// 8 waves as 2M x 4N -> per-wave 128x64 output, acc[8][4].
// LDS buf p at p*65536: A 32KB (2 permuted halves of 16KB), B 32KB at +32768.
// A half mh holds rows m with ((m>>6)&1)==mh at ra=(m&63)+((m>>7)<<6).
// B half nh holds rows c with ((c>>5)&1)==nh at rb=(c&31)+((c>>6)<<5).
// Per K-tile: 4 phases = quadrants (0,0),(0,1),(1,1),(1,0); stage next-tile
// halves A0,B0,B1,A1 (one per phase); vmcnt(4) at ends of p0,p1,p3.
__device__ __forceinline__ void gemm_core3(const char* __restrict__ Ab,
                                           const char* __restrict__ Bb,
                                           char* lds, fx4 acc[8][4]) {
  const int t = threadIdx.x;
  const int l = t & 63;
  const int w = t >> 6;
  const int wm = w >> 2, wn = w & 3;

  #define STAGE_AH(buf, kt, hf, j) do {                              \
    int ra_ = (j) * 64 + (t >> 3);                                   \
    int col_ = (t & 7) * 16;                                         \
    int m_ = (ra_ & 63) | ((ra_ >> 6) << 7) | ((hf) << 6);           \
    gload16(Ab + m_ * 1024 + (kt) * 128 + (col_ ^ ((ra_ & 7) << 4)), \
            lds + (buf) * 65536 + (hf) * 16384 + (j) * 8192 + t * 16); \
  } while (0)
  #define STAGE_BH(buf, kt, hf, j) do {                              \
    int rb_ = (j) * 64 + (t >> 3);                                   \
    int col_ = (t & 7) * 16;                                         \
    int c_ = (rb_ & 31) | ((rb_ >> 5) << 6) | ((hf) << 5);           \
    gload16(Bb + c_ * 1024 + (kt) * 128 + (col_ ^ ((rb_ & 7) << 4)), \
            lds + (buf) * 65536 + 32768 + (hf) * 16384 + (j) * 8192 + t * 16); \
  } while (0)

  // prologue: stage tile 0 halves in consumption order A0,B0,B1,A1
  STAGE_AH(0, 0, 0, 0); STAGE_AH(0, 0, 0, 1);
  STAGE_BH(0, 0, 0, 0); STAGE_BH(0, 0, 0, 1);
  STAGE_BH(0, 0, 1, 0); STAGE_BH(0, 0, 1, 1);
  STAGE_AH(0, 0, 1, 0); STAGE_AH(0, 0, 1, 1);
  asm volatile("s_waitcnt vmcnt(4)" ::: "memory");   // A0,B0 landed
  __builtin_amdgcn_s_barrier();
  FENCE();
  __builtin_amdgcn_sched_barrier(0);

  #pragma unroll 1
  for (int kt = 0; kt < 8; ++kt) {
    const char* As = lds + (kt & 1) * 65536;
    const char* Bs = As + 32768;
    const int nb = (kt + 1) & 1;
    const bool nt = (kt < 7);
    bhalf8 a[8], b0[4], b1[4];

    // ---- p0: quadrant (mh0,nh0); read A0(8) B0(4); stage next A0 ----
    #pragma unroll
    for (int ks = 0; ks < 2; ++ks) {
      const int kb = ks * 64 + ((l >> 4) * 16);
      #pragma unroll
      for (int fm = 0; fm < 4; ++fm) {
        int ra = wm * 64 + fm * 16 + (l & 15);
        a[ks * 4 + fm] = *(const bhalf8*)(As + ra * 128 + (kb ^ ((ra & 7) << 4)));
      }
      #pragma unroll
      for (int fn = 0; fn < 2; ++fn) {
        int rb = wn * 32 + fn * 16 + (l & 15);
        b0[ks * 2 + fn] = *(const bhalf8*)(Bs + rb * 128 + (kb ^ ((rb & 7) << 4)));
      }
    }
    if (nt) { STAGE_AH(nb, kt + 1, 0, 0); STAGE_AH(nb, kt + 1, 0, 1); }
    __builtin_amdgcn_s_barrier();
    asm volatile("s_waitcnt lgkmcnt(0)" ::: "memory");
    __builtin_amdgcn_sched_barrier(0);
    __builtin_amdgcn_s_setprio(1);
    #pragma unroll
    for (int ks = 0; ks < 2; ++ks)
      #pragma unroll
      for (int fm = 0; fm < 4; ++fm)
        #pragma unroll
        for (int fn = 0; fn < 2; ++fn)
          acc[fm][fn] = MFMA16(a[ks * 4 + fm], b0[ks * 2 + fn], acc[fm][fn]);
    __builtin_amdgcn_s_setprio(0);
    if (nt) asm volatile("s_waitcnt vmcnt(4)" ::: "memory");
    else    asm volatile("s_waitcnt vmcnt(2)" ::: "memory");
    __builtin_amdgcn_s_barrier();
    FENCE();
    __builtin_amdgcn_sched_barrier(0);

    // ---- p1: quadrant (mh0,nh1); read B1(4); stage next B0 ----
    #pragma unroll
    for (int ks = 0; ks < 2; ++ks) {
      const int kb = ks * 64 + ((l >> 4) * 16);
      #pragma unroll
      for (int fn = 0; fn < 2; ++fn) {
        int rb = wn * 32 + fn * 16 + (l & 15);
        b1[ks * 2 + fn] = *(const bhalf8*)(Bs + 16384 + rb * 128 + (kb ^ ((rb & 7) << 4)));
      }
    }
    if (nt) { STAGE_BH(nb, kt + 1, 0, 0); STAGE_BH(nb, kt + 1, 0, 1); }
    __builtin_amdgcn_s_barrier();
    asm volatile("s_waitcnt lgkmcnt(0)" ::: "memory");
    __builtin_amdgcn_sched_barrier(0);
    __builtin_amdgcn_s_setprio(1);
    #pragma unroll
    for (int ks = 0; ks < 2; ++ks)
      #pragma unroll
      for (int fm = 0; fm < 4; ++fm)
        #pragma unroll
        for (int fn = 0; fn < 2; ++fn)
          acc[fm][2 + fn] = MFMA16(a[ks * 4 + fm], b1[ks * 2 + fn], acc[fm][2 + fn]);
    __builtin_amdgcn_s_setprio(0);
    if (nt) asm volatile("s_waitcnt vmcnt(4)" ::: "memory");
    else    asm volatile("s_waitcnt vmcnt(0)" ::: "memory");
    __builtin_amdgcn_s_barrier();
    FENCE();
    __builtin_amdgcn_sched_barrier(0);

    // ---- p2: quadrant (mh1,nh1); read A1(8); stage next B1 ----
    #pragma unroll
    for (int ks = 0; ks < 2; ++ks) {
      const int kb = ks * 64 + ((l >> 4) * 16);
      #pragma unroll
      for (int fm = 0; fm < 4; ++fm) {
        int ra = wm * 64 + fm * 16 + (l & 15);
        a[ks * 4 + fm] = *(const bhalf8*)(As + 16384 + ra * 128 + (kb ^ ((ra & 7) << 4)));
      }
    }
    if (nt) { STAGE_BH(nb, kt + 1, 1, 0); STAGE_BH(nb, kt + 1, 1, 1); }
    __builtin_amdgcn_s_barrier();
    asm volatile("s_waitcnt lgkmcnt(0)" ::: "memory");
    __builtin_amdgcn_sched_barrier(0);
    __builtin_amdgcn_s_setprio(1);
    #pragma unroll
    for (int ks = 0; ks < 2; ++ks)
      #pragma unroll
      for (int fm = 0; fm < 4; ++fm)
        #pragma unroll
        for (int fn = 0; fn < 2; ++fn)
          acc[4 + fm][2 + fn] = MFMA16(a[ks * 4 + fm], b1[ks * 2 + fn], acc[4 + fm][2 + fn]);
    __builtin_amdgcn_s_setprio(0);
    __builtin_amdgcn_s_barrier();
    FENCE();
    __builtin_amdgcn_sched_barrier(0);

    // ---- p3: quadrant (mh1,nh0); reuse A1,B0; stage next A1 ----
    if (nt) { STAGE_AH(nb, kt + 1, 1, 0); STAGE_AH(nb, kt + 1, 1, 1); }
    __builtin_amdgcn_s_barrier();
    __builtin_amdgcn_s_setprio(1);
    #pragma unroll
    for (int ks = 0; ks < 2; ++ks)
      #pragma unroll
      for (int fm = 0; fm < 4; ++fm)
        #pragma unroll
        for (int fn = 0; fn < 2; ++fn)
          acc[4 + fm][fn] = MFMA16(a[ks * 4 + fm], b0[ks * 2 + fn], acc[4 + fm][fn]);
    __builtin_amdgcn_s_setprio(0);
    if (nt) asm volatile("s_waitcnt vmcnt(4)" ::: "memory");
    __builtin_amdgcn_s_barrier();
    FENCE();
    __builtin_amdgcn_sched_barrier(0);
  }
  #undef STAGE_AH
  #undef STAGE_BH
}

// ---------------- K1: qkv GEMM + fused q-softmax / k-exp / per-block context partials ----------------
// grid 384 = 64 M-tiles x 6 N-tiles of 256 cols. tN 0,1: Q. tN 2..5: heads {2(tN-2), 2(tN-2)+1}
__global__ __launch_bounds__(512, 2)
void k_qkv_gemm(const char* __restrict__ xb, const char* __restrict__ wqT,
                u16* __restrict__ qhat, float* __restrict__ ctx_part,
                float* __restrict__ z_part) {
  __shared__ __align__(16) char lds[131072];
  const int bx = blockIdx.x;
  const int tM = bx & 63, tN = bx >> 6;
  fx4 acc[8][4];
  const fx4 z4 = {0.f, 0.f, 0.f, 0.f};
  #pragma unroll
  for (int i = 0; i < 8; ++i)
    #pragma unroll
    for (int j = 0; j < 4; ++j) acc[i][j] = z4;

  gemm_core3(xb + tM * 262144, wqT + tN * 262144, lds, acc);

  const int t = threadIdx.x, w = t >> 6, l = t & 63;
  const int wm = w >> 2, wn = w & 3;

  if (tN < 2) {
    // q-softmax: wave's 64-col span = exactly one head
    const int m0 = tM * 256 + wm * 128;
    const int c0 = tN * 256 + wn * 64;
    #pragma unroll
    for (int i = 0; i < 8; ++i) {
      #pragma unroll
      for (int j = 0; j < 4; ++j)
        #pragma unroll
        for (int r = 0; r < 4; ++r)
          acc[i][j][r] = __expf(acc[i][j][r]);
      fx4 s = acc[i][0] + acc[i][1] + acc[i][2] + acc[i][3];
      fx4 inv;
      #pragma unroll
      for (int r = 0; r < 4; ++r) {
        float sv = s[r];
        sv += __shfl_xor(sv, 1, 64);
        sv += __shfl_xor(sv, 2, 64);
        sv += __shfl_xor(sv, 4, 64);
        sv += __shfl_xor(sv, 8, 64);
        inv[r] = 1.0f / sv;
      }
      #pragma unroll
      for (int j = 0; j < 4; ++j)
        #pragma unroll
        for (int r = 0; r < 4; ++r) {
          int m = m0 + i * 16 + ((l >> 4) * 4) + r;
          int c = c0 + j * 16 + (l & 15);
          qhat[m * 512 + c] = f2bf(acc[i][j][r] * inv[r]);
        }
    }
  } else {
    const int j2 = tN - 2;
    const int b = tM >> 4, mt = tM & 15;
    const int hl = wn >> 1;               // head within tile
    const bool isK = ((wn & 1) == 0);
    const int bh = b * 8 + j2 * 2 + hl;
    char* kbuf = lds + hl * 65536;        // [64 d][256 n] bf16 swizzled
    char* vbuf = kbuf + 32768;
    char* dstb = isK ? kbuf : vbuf;
    #pragma unroll
    for (int i = 0; i < 8; ++i)
      #pragma unroll
      for (int j = 0; j < 4; ++j) {
        int d = j * 16 + (l & 15);
        int n0 = wm * 128 + i * 16 + ((l >> 4) * 4);
        US4 p;
        #pragma unroll
        for (int r = 0; r < 4; ++r) {
          float v = acc[i][j][r];
          if (isK) { float tt = v > 0.f ? v + 1.f : __expf(v); v = __expf(tt); }
          p.v[r] = f2bf(v);
        }
        *(US4*)(dstb + d * 512 + ((2 * n0) ^ ((d & 7) << 4))) = p;
      }
    __syncthreads();
    // ctx[d][e] = sum_n khat[d][n]*v[e][n]; 4 waves/head, 16 d-rows each
    const int d0 = (wm * 2 + (wn & 1)) * 16;
    fx4 cacc[4]; fx4 zacc = z4;
    #pragma unroll
    for (int fe = 0; fe < 4; ++fe) cacc[fe] = z4;
    bhalf8 ones;
    #pragma unroll
    for (int i = 0; i < 8; ++i) ones[i] = (short)0x3F80;  // bf16 1.0
    #pragma unroll
    for (int kk = 0; kk < 8; ++kk) {
      int kb = kk * 64 + ((l >> 4) * 16);
      int d = d0 + (l & 15);
      bhalf8 a = *(const bhalf8*)(kbuf + d * 512 + (kb ^ ((d & 7) << 4)));
      #pragma unroll
      for (int fe = 0; fe < 4; ++fe) {
        int e = fe * 16 + (l & 15);
        bhalf8 bv = *(const bhalf8*)(vbuf + e * 512 + (kb ^ ((e & 7) << 4)));
        cacc[fe] = MFMA16(a, bv, cacc[fe]);
      }
      zacc = MFMA16(a, ones, zacc);
    }
    float* cp = ctx_part + (bh * 16 + mt) * 4096;
    #pragma unroll
    for (int fe = 0; fe < 4; ++fe)
      #pragma unroll
      for (int r = 0; r < 4; ++r)
        cp[(d0 + (l >> 4) * 4 + r) * 64 + fe * 16 + (l & 15)] = cacc[fe][r];
    if ((l & 15) == 0) {
      #pragma unroll
      for (int r = 0; r < 4; ++r)
        z_part[(bh * 16 + mt) * 64 + d0 + (l >> 4) * 4 + r] = zacc[r];
    }
  }
}

// ---------------- K2: reduce ctx partials over the 16 M-blocks ----------------
__global__ __launch_bounds__(256)
void k_reduce(const float* __restrict__ ctx_part, float* __restrict__ ctx32) {
  const int bx = blockIdx.x;    // 512 = 32 bh x 16 slices
  const int bh = bx >> 4;
  const int idx = (bx & 15) * 256 + threadIdx.x;
  float s = 0.f;
  #pragma unroll
  for (int mt = 0; mt < 16; ++mt)
    s += ctx_part[(bh * 16 + mt) * 4096 + idx];
  ctx32[bh * 4096 + idx] = s;
}

// ---------------- K3: W2T[b][c][hd] = sum_e (ctx[d][e]/Z[d]) * wp[h*64+e][c]  (bf16 MFMA) ----------------
__global__ __launch_bounds__(256, 1)
void k_w2(const float* __restrict__ ctx32, const float* __restrict__ z_part,
          const u16* __restrict__ wpT, u16* __restrict__ W2T) {
  const int bh = blockIdx.x;            // 32
  const int b = bh >> 3, h = bh & 7;
  __shared__ float zinv[64];
  __shared__ __align__(16) u16 alds[64][72];
  const int t = threadIdx.x;
  if (t < 64) {
    float zs = 0.f;
    #pragma unroll
    for (int mt = 0; mt < 16; ++mt) zs += z_part[(bh * 16 + mt) * 64 + t];
    zinv[t] = 1.0f / zs;
  }
  __syncthreads();
  #pragma unroll
  for (int i = 0; i < 16; ++i) {
    int idx = i * 256 + t;
    int d = idx >> 6, e = idx & 63;
    alds[d][e] = f2bf(ctx32[bh * 4096 + idx] * zinv[d]);
  }
  __syncthreads();
  const int w = t >> 6, l = t & 63;
  fx4 acc[4][8];
  const fx4 z4 = {0.f, 0.f, 0.f, 0.f};
  #pragma unroll
  for (int i = 0; i < 4; ++i)
    #pragma unroll
    for (int j = 0; j < 8; ++j) acc[i][j] = z4;
  #pragma unroll
  for (int ks = 0; ks < 2; ++ks) {
    bhalf8 af[4];
    #pragma unroll
    for (int fm = 0; fm < 4; ++fm) {
      int row = fm * 16 + (l & 15);
      af[fm] = *(const bhalf8*)((const char*)alds + row * 144 + ks * 64 + ((l >> 4) * 16));
    }
    #pragma unroll
    for (int fn = 0; fn < 8; ++fn) {
      int c = w * 128 + fn * 16 + (l & 15);
      bhalf8 bv = *(const bhalf8*)(wpT + c * 512 + h * 64 + ks * 32 + ((l >> 4) * 8));
      #pragma unroll
      for (int fm = 0; fm < 4; ++fm)
        acc[fm][fn] = MFMA16(af[fm], bv, acc[fm][fn]);
    }
  }
  #pragma unroll
  for (int fm = 0; fm < 4; ++fm)
    #pragma unroll
    for (int fn = 0; fn < 8; ++fn) {
      int c = w * 128 + fn * 16 + (l & 15);
      int d0 = fm * 16 + ((l >> 4) * 4);
      US4 p;
      #pragma unroll
      for (int r = 0; r < 4; ++r) p.v[r] = f2bf(acc[fm][fn][r]);
      *(US4*)(W2T + (b * 512 + c) * 512 + h * 64 + d0) = p;
    }
}

// ---------------- K4: final GEMM  out = qhat @ W2_b + bias ----------------
// grid 128 = 64 M-tiles x 2 N-tiles of 256
__global__ __launch_bounds__(512, 2)
void k_out_gemm(const char* __restrict__ qhat, const char* __restrict__ W2T,
                const float* __restrict__ bproj, float* __restrict__ outp) {
  __shared__ __align__(16) char lds[131072];
  const int bx = blockIdx.x;
  const int tM = bx & 63, tN = bx >> 6;
  const int b = tM >> 4;
  fx4 acc[8][4];
  const fx4 z4 = {0.f, 0.f, 0.f, 0.f};
  #pragma unroll
  for (int i = 0; i < 8; ++i)
    #pragma unroll
    for (int j = 0; j < 4; ++j) acc[i][j] = z4;

  gemm_core3(qhat + tM * 262144, W2T + b * 524288 + tN * 262144, lds, acc);

  const int t = threadIdx.x, w = t >> 6, l = t & 63;
  const int wm = w >> 2, wn = w & 3;
  const int m0 = tM * 256 + wm * 128;
  const int c0 = tN * 256 + wn * 64;
  #pragma unroll
  for (int i = 0; i < 8; ++i)
    #pragma unroll
    for (int j = 0; j < 4; ++j) {
      int c = c0 + j * 16 + (l & 15);
      float bp = bproj[c];
      #pragma unroll
      for (int r = 0; r < 4; ++r) {
        int m = m0 + i * 16 + ((l >> 4) * 4) + r;
        outp[m * 512 + c] = acc[i][j][r] + bp;
      }
    }
}

extern "C" void kernel_launch(void* const* d_in, const int* in_sizes, int n_in,
                              void* d_out, int out_size, void* d_ws, size_t ws_size,
                              hipStream_t stream) {
  (void)in_sizes; (void)n_in; (void)out_size;
  const float* x     = (const float*)d_in[0];
  const float* wqkv  = (const float*)d_in[1];
  const float* wproj = (const float*)d_in[2];
  const float* bproj = (const float*)d_in[3];
  float* outp = (float*)d_out;
  char* ws = (char*)d_ws;

  char* xb   = ws;                 // 16384*512*2       = 16,777,216
  char* wqT  = ws + 16777216;      // 1536*512*2        =  1,572,864
  char* wpT  = ws + 18350080;      // 512*512*2         =    524,288
  char* qhat = ws + 18874368;      // 16384*512*2       = 16,777,216
  char* ctxp = ws + 35651584;      // 32*16*4096*4      =  8,388,608
  char* zp   = ws + 44040192;      // 32*16*64*4        =    131,072
  char* ctx32= ws + 44171264;      // 32*4096*4         =    524,288
  char* w2t  = ws + 44695552;      // 4*512*512*2       =  2,097,152  (end 46,792,704)
  if (ws_size < 46792704) return;

  k_conv<<<8192, 256, 0, stream>>>(x, (u16*)xb, 2097152);
  k_transpose<<<192, 256, 0, stream>>>(wqkv, (u16*)wqT, 512, 1536, 8, 1);
  k_transpose<<<64, 256, 0, stream>>>(wproj, (u16*)wpT, 512, 512, 8, 0);
  k_qkv_gemm<<<384, 512, 0, stream>>>(xb, wqT, (u16*)qhat, (float*)ctxp, (float*)zp);
  k_reduce<<<512, 256, 0, stream>>>((const float*)ctxp, (float*)ctx32);
  k_w2<<<32, 256, 0, stream>>>((const float*)ctx32, (const float*)zp, (const u16*)wpT, (u16*)w2t);
  k_out_gemm<<<128, 512, 0, stream>>>(qhat, w2t, bproj, outp);
}